// Round 2
// baseline (292.563 us; speedup 1.0000x reference)
//
#include <hip/hip_runtime.h>

// Problem constants
constexpr int kT = 512;     // sequence length
constexpr int kF = 64;      // input features
constexpr int kC = 256;     // f_out
constexpr int kH = 4;       // heads
constexpr int kHD = 64;     // head dim
constexpr int kBN = 128;    // B*N independent problems

typedef __attribute__((ext_vector_type(4))) float f32x4;
typedef __attribute__((ext_vector_type(8))) short s16x8;

__device__ inline unsigned short f2bf(float f) {
  unsigned int u = __float_as_uint(f);
  u += 0x7fff + ((u >> 16) & 1);  // round-to-nearest-even
  return (unsigned short)(u >> 16);
}

// ---------------------------------------------------------------------------
// Kernel 1: QKV projection.  Per block: one (bn, 128-row t-chunk).
// Computes [768 c][128 t] = Wt[768][64] * xT[128][64]^T via MFMA.
// Q gets (val + bias) * 0.125 folded in (score scale).
// Layout out: Qw/Kw/Vw [bn][h][t][d] bf16.
// ---------------------------------------------------------------------------
__global__ __launch_bounds__(256) void k_qkv(
    const float* __restrict__ x,
    const float* __restrict__ Wq, const float* __restrict__ bq,
    const float* __restrict__ Wk, const float* __restrict__ bk,
    const float* __restrict__ Wv, const float* __restrict__ bv,
    unsigned short* __restrict__ Qw, unsigned short* __restrict__ Kw,
    unsigned short* __restrict__ Vw, int bn0) {
  __shared__ __align__(16) unsigned short xT[128][72];   // [t][f], pad 72
  __shared__ __align__(16) unsigned short Wt[768][72];   // [c][f], pad 72

  const int tid = threadIdx.x;
  const int lbn = blockIdx.x >> 2;
  const int tch = blockIdx.x & 3;
  const float* xb = x + (size_t)(bn0 + lbn) * kF * kT + tch * 128;

  // Stage W^T (q|k|v concatenated along c) as bf16
  for (int idx = tid; idx < 768 * 64; idx += 256) {
    int arr = idx >> 14;
    int rem = idx & 16383;
    int f = rem >> 8;
    int cc = rem & 255;
    const float* Wsrc = (arr == 0) ? Wq : (arr == 1) ? Wk : Wv;
    Wt[arr * 256 + cc][f] = f2bf(Wsrc[f * 256 + cc]);
  }
  // Stage x^T chunk as bf16
  for (int idx = tid; idx < 64 * 128; idx += 256) {
    int f = idx >> 7, tl = idx & 127;
    xT[tl][f] = f2bf(xb[f * kT + tl]);
  }
  __syncthreads();

  const int lane = tid & 63, wid = tid >> 6;
  const int lr = lane & 15, lg = lane >> 4;

  // Preload all B-frags (xT) for this wave: 8 t-tiles x 2 k-chunks
  s16x8 bfr[8][2];
#pragma unroll
  for (int tj = 0; tj < 8; ++tj)
#pragma unroll
    for (int kk = 0; kk < 2; ++kk)
      bfr[tj][kk] = *(const s16x8*)&xT[tj * 16 + lr][kk * 32 + lg * 8];

  for (int i = 0; i < 12; ++i) {
    const int ci = wid * 12 + i;
    const int c0 = ci * 16;
    s16x8 af0 = *(const s16x8*)&Wt[c0 + lr][lg * 8];
    s16x8 af1 = *(const s16x8*)&Wt[c0 + lr][32 + lg * 8];

    f32x4 acc[8];
#pragma unroll
    for (int tj = 0; tj < 8; ++tj) {
      f32x4 a = {0.f, 0.f, 0.f, 0.f};
      a = __builtin_amdgcn_mfma_f32_16x16x32_bf16(af0, bfr[tj][0], a, 0, 0, 0);
      a = __builtin_amdgcn_mfma_f32_16x16x32_bf16(af1, bfr[tj][1], a, 0, 0, 0);
      acc[tj] = a;
    }

    const int arr = c0 >> 8;
    const int h = (c0 & 255) >> 6;
    const int dbase = (c0 & 63) + lg * 4;
    const float* bsrc = (arr == 0) ? bq : (arr == 1) ? bk : bv;
    const float scale = (arr == 0) ? 0.125f : 1.0f;
    float b0 = bsrc[h * 64 + dbase + 0];
    float b1 = bsrc[h * 64 + dbase + 1];
    float b2 = bsrc[h * 64 + dbase + 2];
    float b3 = bsrc[h * 64 + dbase + 3];
    unsigned short* dst =
        ((arr == 0) ? Qw : (arr == 1) ? Kw : Vw) +
        (size_t)(lbn * kH + h) * kT * kHD;

#pragma unroll
    for (int tj = 0; tj < 8; ++tj) {
      int t = tch * 128 + tj * 16 + lr;
      float v0 = (acc[tj][0] + b0) * scale;
      float v1 = (acc[tj][1] + b1) * scale;
      float v2 = (acc[tj][2] + b2) * scale;
      float v3 = (acc[tj][3] + b3) * scale;
      unsigned long long pk =
          (unsigned long long)f2bf(v0) |
          ((unsigned long long)f2bf(v1) << 16) |
          ((unsigned long long)f2bf(v2) << 32) |
          ((unsigned long long)f2bf(v3) << 48);
      *(unsigned long long*)(dst + (size_t)t * kHD + dbase) = pk;
    }
  }
}

// ---------------------------------------------------------------------------
// Kernel 2: flash attention per (bn, head). 512 threads = 8 waves.
// Each wave owns 64 q-rows (4 tiles of 16), iterates 16 chunks of 32 keys.
// K in LDS [512][72]; V transposed in LDS [64][520]; P staged per-wave.
// Writes attn-out bf16 to Aw [bn][t][c] (c = h*64+d).
// ---------------------------------------------------------------------------
__global__ __launch_bounds__(512) void k_attn(
    const unsigned short* __restrict__ Qw, const unsigned short* __restrict__ Kw,
    const unsigned short* __restrict__ Vw, unsigned short* __restrict__ Aw) {
  __shared__ __align__(16) unsigned short Kl[512][72];
  __shared__ __align__(16) unsigned short Vt[64][520];
  __shared__ __align__(16) unsigned short Pl[8][16][40];

  const int tid = threadIdx.x;
  const int lbn = blockIdx.x >> 2;
  const int h = blockIdx.x & 3;
  const size_t hb = (size_t)(lbn * kH + h) * kT * kHD;

  const uint4* Ksrc = (const uint4*)(Kw + hb);
  const uint4* Vsrc = (const uint4*)(Vw + hb);
#pragma unroll
  for (int i = 0; i < 8; ++i) {
    int cidx = tid + i * 512;
    int t = cidx >> 3, c8 = cidx & 7;
    uint4 kv = Ksrc[cidx];
    *(uint4*)&Kl[t][c8 * 8] = kv;
    union { uint4 v; unsigned short u[8]; } tmp;
    tmp.v = Vsrc[cidx];
#pragma unroll
    for (int j = 0; j < 8; ++j) Vt[c8 * 8 + j][t] = tmp.u[j];
  }
  __syncthreads();

  const int lane = tid & 63, wid = tid >> 6;
  const int lr = lane & 15, lg = lane >> 4;
  const unsigned short* Qb = Qw + hb;
  unsigned short* Ab = Aw + (size_t)lbn * kT * kC + h * kHD;

  for (int qt = 0; qt < 4; ++qt) {
    const int qbase = wid * 64 + qt * 16;
    s16x8 qf0 = *(const s16x8*)(Qb + (size_t)(qbase + lr) * kHD + lg * 8);
    s16x8 qf1 = *(const s16x8*)(Qb + (size_t)(qbase + lr) * kHD + 32 + lg * 8);

    f32x4 o[4] = {{0,0,0,0},{0,0,0,0},{0,0,0,0},{0,0,0,0}};
    float m[4] = {-3e38f, -3e38f, -3e38f, -3e38f};
    float l[4] = {0.f, 0.f, 0.f, 0.f};

    for (int kc = 0; kc < 16; ++kc) {
      const int kb = kc * 32;
      f32x4 s0 = {0,0,0,0}, s1 = {0,0,0,0};
      s16x8 k00 = *(const s16x8*)&Kl[kb + lr][lg * 8];
      s16x8 k01 = *(const s16x8*)&Kl[kb + lr][32 + lg * 8];
      s16x8 k10 = *(const s16x8*)&Kl[kb + 16 + lr][lg * 8];
      s16x8 k11 = *(const s16x8*)&Kl[kb + 16 + lr][32 + lg * 8];
      s0 = __builtin_amdgcn_mfma_f32_16x16x32_bf16(qf0, k00, s0, 0, 0, 0);
      s0 = __builtin_amdgcn_mfma_f32_16x16x32_bf16(qf1, k01, s0, 0, 0, 0);
      s1 = __builtin_amdgcn_mfma_f32_16x16x32_bf16(qf0, k10, s1, 0, 0, 0);
      s1 = __builtin_amdgcn_mfma_f32_16x16x32_bf16(qf1, k11, s1, 0, 0, 0);

      float tm[4], al[4], rs[4], p0[4], p1[4];
#pragma unroll
      for (int r = 0; r < 4; ++r) tm[r] = fmaxf(s0[r], s1[r]);
#pragma unroll
      for (int off = 8; off; off >>= 1)
#pragma unroll
        for (int r = 0; r < 4; ++r) tm[r] = fmaxf(tm[r], __shfl_xor(tm[r], off));
#pragma unroll
      for (int r = 0; r < 4; ++r) {
        float mn = fmaxf(m[r], tm[r]);
        al[r] = __expf(m[r] - mn);
        m[r] = mn;
        p0[r] = __expf(s0[r] - mn);
        p1[r] = __expf(s1[r] - mn);
        rs[r] = p0[r] + p1[r];
      }
#pragma unroll
      for (int off = 8; off; off >>= 1)
#pragma unroll
        for (int r = 0; r < 4; ++r) rs[r] += __shfl_xor(rs[r], off);
#pragma unroll
      for (int r = 0; r < 4; ++r) {
        l[r] = l[r] * al[r] + rs[r];
        o[0][r] *= al[r]; o[1][r] *= al[r];
        o[2][r] *= al[r]; o[3][r] *= al[r];
        int prow = lg * 4 + r;
        Pl[wid][prow][lr] = f2bf(p0[r]);
        Pl[wid][prow][16 + lr] = f2bf(p1[r]);
      }
      s16x8 pa = *(const s16x8*)&Pl[wid][lr][lg * 8];
#pragma unroll
      for (int dt = 0; dt < 4; ++dt) {
        s16x8 vb = *(const s16x8*)&Vt[dt * 16 + lr][kb + lg * 8];
        o[dt] = __builtin_amdgcn_mfma_f32_16x16x32_bf16(pa, vb, o[dt], 0, 0, 0);
      }
    }

#pragma unroll
    for (int r = 0; r < 4; ++r) {
      float inv = 1.0f / l[r];
      int q = qbase + lg * 4 + r;
      unsigned short* orow = Ab + (size_t)q * kC;
#pragma unroll
      for (int dt = 0; dt < 4; ++dt)
        orow[dt * 16 + lr] = f2bf(o[dt][r] * inv);
    }
  }
}

// ---------------------------------------------------------------------------
// Kernel 3: output projection + bias + transpose.
// Per block: (bn, 128-row t-chunk, 64-col co-chunk). out[bn][co][t] fp32.
// ---------------------------------------------------------------------------
__global__ __launch_bounds__(256) void k_proj(
    const unsigned short* __restrict__ Aw, const float* __restrict__ Wo,
    const float* __restrict__ bo, float* __restrict__ out, int bn0) {
  __shared__ __align__(16) unsigned short Al[128][264];  // [t][c]
  __shared__ __align__(16) unsigned short Wt[64][264];   // [co][c]

  const int tid = threadIdx.x;
  const int lbn = blockIdx.x >> 4;
  const int rest = blockIdx.x & 15;
  const int t0 = (rest >> 2) * 128;
  const int cob = (rest & 3) * 64;

  const uint4* Asrc = (const uint4*)(Aw + ((size_t)lbn * kT + t0) * kC);
#pragma unroll
  for (int i = 0; i < 16; ++i) {
    int idx = tid + i * 256;
    int trow = idx >> 5, cc = idx & 31;
    *(uint4*)&Al[trow][cc * 8] = Asrc[idx];
  }
  for (int idx = tid; idx < 64 * 256; idx += 256) {
    int col = idx & 63, c = idx >> 6;
    Wt[col][c] = f2bf(Wo[c * 256 + cob + col]);
  }
  __syncthreads();

  const int lane = tid & 63, wid = tid >> 6;
  const int lr = lane & 15, lg = lane >> 4;

  s16x8 af[8];
#pragma unroll
  for (int kc = 0; kc < 8; ++kc)
    af[kc] = *(const s16x8*)&Wt[wid * 16 + lr][kc * 32 + lg * 8];
  float b4[4];
#pragma unroll
  for (int r = 0; r < 4; ++r) b4[r] = bo[cob + wid * 16 + lg * 4 + r];

  float* ob = out + (size_t)(bn0 + lbn) * kC * kT;
  for (int tj = 0; tj < 8; ++tj) {
    f32x4 acc = {0.f, 0.f, 0.f, 0.f};
#pragma unroll
    for (int kc = 0; kc < 8; ++kc) {
      s16x8 bfr = *(const s16x8*)&Al[tj * 16 + lr][kc * 32 + lg * 8];
      acc = __builtin_amdgcn_mfma_f32_16x16x32_bf16(af[kc], bfr, acc, 0, 0, 0);
    }
    int t = t0 + tj * 16 + lr;
#pragma unroll
    for (int r = 0; r < 4; ++r) {
      int co = cob + wid * 16 + lg * 4 + r;
      ob[(size_t)co * kT + t] = acc[r] + b4[r];
    }
  }
}

// ---------------------------------------------------------------------------
extern "C" void kernel_launch(void* const* d_in, const int* in_sizes, int n_in,
                              void* d_out, int out_size, void* d_ws, size_t ws_size,
                              hipStream_t stream) {
  const float* x  = (const float*)d_in[0];
  const float* Wq = (const float*)d_in[1];
  const float* bq = (const float*)d_in[2];
  const float* Wk = (const float*)d_in[3];
  const float* bk = (const float*)d_in[4];
  const float* Wv = (const float*)d_in[5];
  const float* bv = (const float*)d_in[6];
  const float* Wo = (const float*)d_in[7];
  const float* bo = (const float*)d_in[8];
  float* out = (float*)d_out;

  // Per-bn workspace: Q + K + V + attn-out, all bf16 = 4 * 131072 * 2 B = 1 MB
  const size_t perbn = (size_t)4 * kT * kC * 2;
  int cap = (int)(ws_size / perbn);
  if (cap > kBN) cap = kBN;
  if (cap < 1) return;  // workspace too small — cannot run

  unsigned short* Q = (unsigned short*)d_ws;
  unsigned short* K = Q + (size_t)cap * kT * kC;
  unsigned short* V = K + (size_t)cap * kT * kC;
  unsigned short* A = V + (size_t)cap * kT * kC;

  for (int s = 0; s < kBN; s += cap) {
    int nb = (kBN - s < cap) ? (kBN - s) : cap;
    k_qkv<<<dim3(nb * 4), dim3(256), 0, stream>>>(x, Wq, bq, Wk, bk, Wv, bv,
                                                  Q, K, V, s);
    k_attn<<<dim3(nb * 4), dim3(512), 0, stream>>>(Q, K, V, A);
    k_proj<<<dim3(nb * 16), dim3(256), 0, stream>>>(A, Wo, bo, out, s);
  }
}

// Round 3
// 184.724 us; speedup vs baseline: 1.5838x; 1.5838x over previous
//
#include <hip/hip_runtime.h>

// Problem constants
constexpr int kT = 512;     // sequence length
constexpr int kF = 64;      // input features
constexpr int kC = 256;     // f_out
constexpr int kH = 4;       // heads
constexpr int kHD = 64;     // head dim
constexpr int kBN = 128;    // B*N independent problems

typedef __attribute__((ext_vector_type(4))) float f32x4;
typedef __attribute__((ext_vector_type(8))) short s16x8;

__device__ inline unsigned short f2bf(float f) {
  unsigned int u = __float_as_uint(f);
  u += 0x7fff + ((u >> 16) & 1);  // round-to-nearest-even
  return (unsigned short)(u >> 16);
}

// ---------------------------------------------------------------------------
// Kernel 0: weight precompute (once per call, not per block).
// WB  [768][64]  = [Wq;Wk;Wv]^T rows c, cols f   (bf16)
// WoT [256][256] = Wo^T rows co, cols c          (bf16)
// ---------------------------------------------------------------------------
__global__ __launch_bounds__(256) void k_prep(
    const float* __restrict__ Wq, const float* __restrict__ Wk,
    const float* __restrict__ Wv, const float* __restrict__ Wo,
    unsigned short* __restrict__ WB, unsigned short* __restrict__ WoT) {
  int i = blockIdx.x * 256 + threadIdx.x;
  const int total = 768 * 64 + 256 * 256;
  for (; i < total; i += gridDim.x * 256) {
    if (i < 768 * 64) {
      int c = i >> 6, f = i & 63;
      int arr = c >> 8, cc = c & 255;
      const float* W = (arr == 0) ? Wq : (arr == 1) ? Wk : Wv;
      WB[i] = f2bf(W[f * 256 + cc]);
    } else {
      int j = i - 768 * 64;
      int co = j >> 8, c = j & 255;
      WoT[j] = f2bf(Wo[c * 256 + co]);
    }
  }
}

// ---------------------------------------------------------------------------
// Kernel 1: QKV projection. Block = (bn, 128-row t-chunk), 256 thr.
// A-frags read directly from L2-hot WB (no weight LDS).
// Q,K out: [bn][h][t][d] bf16 (Q pre-scaled by 0.125). V out: [bn][h][d][t].
// ---------------------------------------------------------------------------
__global__ __launch_bounds__(256) void k_qkv(
    const float* __restrict__ x, const unsigned short* __restrict__ WB,
    const float* __restrict__ bq, const float* __restrict__ bk,
    const float* __restrict__ bv,
    unsigned short* __restrict__ Qw, unsigned short* __restrict__ Kw,
    unsigned short* __restrict__ Vw, int bn0) {
  __shared__ __align__(16) unsigned short xT[128][72];   // [t][f], pad 72

  const int tid = threadIdx.x;
  const int lbn = blockIdx.x >> 2;
  const int tch = blockIdx.x & 3;
  const float* xb = x + (size_t)(bn0 + lbn) * kF * kT + tch * 128;

  for (int idx = tid; idx < 64 * 128; idx += 256) {
    int f = idx >> 7, tl = idx & 127;
    xT[tl][f] = f2bf(xb[f * kT + tl]);
  }
  __syncthreads();

  const int lane = tid & 63, wid = tid >> 6;
  const int lr = lane & 15, lg = lane >> 4;

  s16x8 bfr[8][2];
#pragma unroll
  for (int tj = 0; tj < 8; ++tj)
#pragma unroll
    for (int kk = 0; kk < 2; ++kk)
      bfr[tj][kk] = *(const s16x8*)&xT[tj * 16 + lr][kk * 32 + lg * 8];

  for (int i = 0; i < 12; ++i) {
    const int ci = wid * 12 + i;
    const int c0 = ci * 16;
    s16x8 af0 = *(const s16x8*)(WB + (size_t)(c0 + lr) * 64 + lg * 8);
    s16x8 af1 = *(const s16x8*)(WB + (size_t)(c0 + lr) * 64 + 32 + lg * 8);

    f32x4 acc[8];
#pragma unroll
    for (int tj = 0; tj < 8; ++tj) {
      f32x4 a = {0.f, 0.f, 0.f, 0.f};
      a = __builtin_amdgcn_mfma_f32_16x16x32_bf16(af0, bfr[tj][0], a, 0, 0, 0);
      a = __builtin_amdgcn_mfma_f32_16x16x32_bf16(af1, bfr[tj][1], a, 0, 0, 0);
      acc[tj] = a;
    }

    const int arr = c0 >> 8;
    const int h = (c0 & 255) >> 6;
    const int dbase = (c0 & 63) + lg * 4;
    const float* bsrc = (arr == 0) ? bq : (arr == 1) ? bk : bv;
    const float scale = (arr == 0) ? 0.125f : 1.0f;
    float b0 = bsrc[h * 64 + dbase + 0];
    float b1 = bsrc[h * 64 + dbase + 1];
    float b2 = bsrc[h * 64 + dbase + 2];
    float b3 = bsrc[h * 64 + dbase + 3];

    if (arr < 2) {
      unsigned short* dst = ((arr == 0) ? Qw : Kw) +
                            (size_t)(lbn * kH + h) * kT * kHD;
#pragma unroll
      for (int tj = 0; tj < 8; ++tj) {
        int t = tch * 128 + tj * 16 + lr;
        float v0 = (acc[tj][0] + b0) * scale;
        float v1 = (acc[tj][1] + b1) * scale;
        float v2 = (acc[tj][2] + b2) * scale;
        float v3 = (acc[tj][3] + b3) * scale;
        unsigned long long pk =
            (unsigned long long)f2bf(v0) |
            ((unsigned long long)f2bf(v1) << 16) |
            ((unsigned long long)f2bf(v2) << 32) |
            ((unsigned long long)f2bf(v3) << 48);
        *(unsigned long long*)(dst + (size_t)t * kHD + dbase) = pk;
      }
    } else {
      // V^T: [bn][h][d][t]
      unsigned short* dst = Vw + (size_t)(lbn * kH + h) * kHD * kT;
#pragma unroll
      for (int tj = 0; tj < 8; ++tj) {
        int t = tch * 128 + tj * 16 + lr;
        dst[(size_t)(dbase + 0) * kT + t] = f2bf(acc[tj][0] + b0);
        dst[(size_t)(dbase + 1) * kT + t] = f2bf(acc[tj][1] + b1);
        dst[(size_t)(dbase + 2) * kT + t] = f2bf(acc[tj][2] + b2);
        dst[(size_t)(dbase + 3) * kT + t] = f2bf(acc[tj][3] + b3);
      }
    }
  }
}

// ---------------------------------------------------------------------------
// Kernel 2: flash attention per (bn, head). 1024 threads = 16 waves.
// Swapped QK^T (K as A-operand) -> scores [k][q], k lane-local: in-lane
// softmax with only 2 shfl per 64-key chunk. K,V^T in XOR-swizzled linear
// LDS (64 KB each). P routed via per-wave LDS ping-pong (u32 cvt_pk words).
// Each wave owns 32 q rows (2 tiles of 16); KVBLK = 64.
// ---------------------------------------------------------------------------
__global__ __launch_bounds__(1024, 4) void k_attn(
    const unsigned short* __restrict__ Qw, const unsigned short* __restrict__ Kw,
    const unsigned short* __restrict__ Vw, unsigned short* __restrict__ Aw) {
  __shared__ __align__(16) unsigned char KlB[512 * 128];   // [k][d] swizzled
  __shared__ __align__(16) unsigned char VtB[64 * 1024];   // [d][t] swizzled
  __shared__ __align__(16) unsigned int Plw[16][16][20];   // per-wave [q][kword]

  const int tid = threadIdx.x;
  const int lbn = blockIdx.x >> 2;
  const int h = blockIdx.x & 3;
  const size_t hb = (size_t)(lbn * kH + h) * kT * kHD;

  const uint4* Ksrc = (const uint4*)(Kw + hb);
  const uint4* Vsrc = (const uint4*)(Vw + hb);
#pragma unroll
  for (int i = 0; i < 4; ++i) {
    int cidx = tid + i * 1024;
    int t = cidx >> 3, c8 = cidx & 7;
    *(uint4*)(KlB + ((t * 128 + c8 * 16) ^ ((t & 7) << 4))) = Ksrc[cidx];
    int d = cidx >> 6, t8 = cidx & 63;
    *(uint4*)(VtB + ((d * 1024 + t8 * 16) ^ ((d & 7) << 4))) = Vsrc[cidx];
  }
  __syncthreads();

  const int lane = tid & 63, wid = tid >> 6;
  const int lr = lane & 15, lg = lane >> 4;
  const int swz = (lr & 7) << 4;
  const unsigned short* Qb = Qw + hb;
  unsigned short* Ab = Aw + (size_t)lbn * kT * kC + h * kHD;

  for (int qt = 0; qt < 2; ++qt) {
    const int qbase = wid * 32 + qt * 16;
    s16x8 qf0 = *(const s16x8*)(Qb + (size_t)(qbase + lr) * kHD + lg * 8);
    s16x8 qf1 = *(const s16x8*)(Qb + (size_t)(qbase + lr) * kHD + 32 + lg * 8);

    f32x4 o[4] = {{0,0,0,0},{0,0,0,0},{0,0,0,0},{0,0,0,0}};
    float m = -3e38f, l = 0.f;

    for (int kc = 0; kc < 8; ++kc) {
      const int kb = kc * 64;

      // K A-frags (swizzled LDS): rows kb+16s+lr, two 32-d chunks
      s16x8 kf[4][2];
#pragma unroll
      for (int s = 0; s < 4; ++s) {
        const unsigned char* rp = KlB + (kb + 16 * s + lr) * 128;
        kf[s][0] = *(const s16x8*)(rp + ((lg * 16) ^ swz));
        kf[s][1] = *(const s16x8*)(rp + ((64 + lg * 16) ^ swz));
      }

      // scores: sa[s][r] = S[k = kb+16s+4lg+r][q = qbase+lr]
      f32x4 sa[4];
#pragma unroll
      for (int s = 0; s < 4; ++s) {
        f32x4 z = {0.f, 0.f, 0.f, 0.f};
        z = __builtin_amdgcn_mfma_f32_16x16x32_bf16(kf[s][0], qf0, z, 0, 0, 0);
        z = __builtin_amdgcn_mfma_f32_16x16x32_bf16(kf[s][1], qf1, z, 0, 0, 0);
        sa[s] = z;
      }

      // in-lane max over 16, then 2 shfl across lane-groups
      float tm = sa[0][0];
#pragma unroll
      for (int s = 0; s < 4; ++s)
#pragma unroll
        for (int r = 0; r < 4; ++r) tm = fmaxf(tm, sa[s][r]);
      tm = fmaxf(tm, __shfl_xor(tm, 16));
      tm = fmaxf(tm, __shfl_xor(tm, 32));
      float mn = fmaxf(m, tm);
      float al = __expf(m - mn);
      m = mn;

      float p[4][4];
      float rs = 0.f;
#pragma unroll
      for (int s = 0; s < 4; ++s)
#pragma unroll
        for (int r = 0; r < 4; ++r) {
          p[s][r] = __expf(sa[s][r] - mn);
          rs += p[s][r];
        }
      rs += __shfl_xor(rs, 16);
      rs += __shfl_xor(rs, 32);
      l = l * al + rs;

      // rescale factors for o's q-rows (q = lg*4+r lives at lane lr'=lg*4+r)
      float alq[4];
#pragma unroll
      for (int r = 0; r < 4; ++r)
        alq[r] = __shfl(al, (lane & 48) | (lg * 4 + r));
#pragma unroll
      for (int dt = 0; dt < 4; ++dt)
#pragma unroll
        for (int r = 0; r < 4; ++r) o[dt][r] *= alq[r];

      // P -> bf16 words -> per-wave LDS; PV per 32-k slice
#pragma unroll
      for (int t2 = 0; t2 < 2; ++t2) {
#pragma unroll
        for (int s2 = 0; s2 < 2; ++s2) {
          const int s = 2 * t2 + s2;
#pragma unroll
          for (int i2 = 0; i2 < 2; ++i2) {
            unsigned int w;
            asm("v_cvt_pk_bf16_f32 %0, %1, %2"
                : "=v"(w) : "v"(p[s][2 * i2]), "v"(p[s][2 * i2 + 1]));
            Plw[wid][lr][8 * s2 + 2 * lg + i2] = w;
          }
        }
        s16x8 pa = *(const s16x8*)&Plw[wid][lr][lg * 4];
#pragma unroll
        for (int dt = 0; dt < 4; ++dt) {
          const unsigned char* vp = VtB + (dt * 16 + lr) * 1024;
          s16x8 vb = *(const s16x8*)(vp + (((kb + 32 * t2 + lg * 8) * 2) ^ swz));
          o[dt] = __builtin_amdgcn_mfma_f32_16x16x32_bf16(pa, vb, o[dt], 0, 0, 0);
        }
      }
    }

    // epilogue: o rows are q = qbase + lg*4 + r, cols d = dt*16 + lr
    float linv[4];
#pragma unroll
    for (int r = 0; r < 4; ++r)
      linv[r] = 1.0f / __shfl(l, (lane & 48) | (lg * 4 + r));
#pragma unroll
    for (int r = 0; r < 4; ++r) {
      int q = qbase + lg * 4 + r;
      unsigned short* orow = Ab + (size_t)q * kC;
#pragma unroll
      for (int dt = 0; dt < 4; ++dt)
        orow[dt * 16 + lr] = f2bf(o[dt][r] * linv[r]);
    }
  }
}

// ---------------------------------------------------------------------------
// Kernel 3: output projection + bias + transpose. No LDS; weight frags from
// L2-hot WoT, A frags straight from global (4x reuse via L1).
// Block = (bn, 128-row t-chunk, 64-col co-chunk). out[bn][co][t] fp32.
// ---------------------------------------------------------------------------
__global__ __launch_bounds__(256) void k_proj(
    const unsigned short* __restrict__ Aw, const unsigned short* __restrict__ WoT,
    const float* __restrict__ bo, float* __restrict__ out, int bn0) {
  const int tid = threadIdx.x;
  const int lbn = blockIdx.x >> 4;
  const int rest = blockIdx.x & 15;
  const int t0 = (rest >> 2) * 128;
  const int cob = (rest & 3) * 64;
  const int lane = tid & 63, wid = tid >> 6;
  const int lr = lane & 15, lg = lane >> 4;

  s16x8 af[8];
#pragma unroll
  for (int kc = 0; kc < 8; ++kc)
    af[kc] = *(const s16x8*)(WoT + (size_t)(cob + wid * 16 + lr) * 256 +
                             kc * 32 + lg * 8);
  float b4[4];
#pragma unroll
  for (int r = 0; r < 4; ++r) b4[r] = bo[cob + wid * 16 + lg * 4 + r];

  const unsigned short* Ab = Aw + (size_t)lbn * kT * kC;
  float* ob = out + (size_t)(bn0 + lbn) * kC * kT;

  for (int tj = 0; tj < 8; ++tj) {
    f32x4 acc = {0.f, 0.f, 0.f, 0.f};
#pragma unroll
    for (int kc = 0; kc < 8; ++kc) {
      s16x8 bfr = *(const s16x8*)(Ab + (size_t)(t0 + tj * 16 + lr) * 256 +
                                  kc * 32 + lg * 8);
      acc = __builtin_amdgcn_mfma_f32_16x16x32_bf16(af[kc], bfr, acc, 0, 0, 0);
    }
    int t = t0 + tj * 16 + lr;
#pragma unroll
    for (int r = 0; r < 4; ++r) {
      int co = cob + wid * 16 + lg * 4 + r;
      ob[(size_t)co * kT + t] = acc[r] + b4[r];
    }
  }
}

// ---------------------------------------------------------------------------
extern "C" void kernel_launch(void* const* d_in, const int* in_sizes, int n_in,
                              void* d_out, int out_size, void* d_ws, size_t ws_size,
                              hipStream_t stream) {
  const float* x  = (const float*)d_in[0];
  const float* Wq = (const float*)d_in[1];
  const float* bq = (const float*)d_in[2];
  const float* Wk = (const float*)d_in[3];
  const float* bk = (const float*)d_in[4];
  const float* Wv = (const float*)d_in[5];
  const float* bv = (const float*)d_in[6];
  const float* Wo = (const float*)d_in[7];
  const float* bo = (const float*)d_in[8];
  float* out = (float*)d_out;

  // ws layout: WB bf16 [768*64] | WoT bf16 [256*256] | Q | K | V | A (per-bn 1MB)
  const size_t wElems = 768 * 64 + 256 * 256;      // 114688 shorts = 229376 B
  const size_t perbn = (size_t)4 * kT * kC * 2;    // 1 MB
  if (ws_size < wElems * 2 + perbn) return;
  int cap = (int)((ws_size - wElems * 2) / perbn);
  if (cap > kBN) cap = kBN;

  unsigned short* WB  = (unsigned short*)d_ws;
  unsigned short* WoT = WB + 768 * 64;
  unsigned short* Q = WB + wElems;
  unsigned short* K = Q + (size_t)cap * kT * kC;
  unsigned short* V = K + (size_t)cap * kT * kC;
  unsigned short* A = V + (size_t)cap * kT * kC;

  k_prep<<<dim3(448), dim3(256), 0, stream>>>(Wq, Wk, Wv, Wo, WB, WoT);

  for (int s = 0; s < kBN; s += cap) {
    int nb = (kBN - s < cap) ? (kBN - s) : cap;
    k_qkv<<<dim3(nb * 4), dim3(256), 0, stream>>>(x, WB, bq, bk, bv,
                                                  Q, K, V, s);
    k_attn<<<dim3(nb * 4), dim3(1024), 0, stream>>>(Q, K, V, A);
    k_proj<<<dim3(nb * 16), dim3(256), 0, stream>>>(A, WoT, bo, out, s);
  }
}

// Round 4
// 153.053 us; speedup vs baseline: 1.9115x; 1.2069x over previous
//
#include <hip/hip_runtime.h>

// Problem constants
constexpr int kT = 512;     // sequence length
constexpr int kF = 64;      // input features
constexpr int kC = 256;     // f_out
constexpr int kH = 4;       // heads
constexpr int kHD = 64;     // head dim
constexpr int kBN = 128;    // B*N independent problems

typedef __attribute__((ext_vector_type(4))) float f32x4;
typedef __attribute__((ext_vector_type(8))) short s16x8;

__device__ inline unsigned short f2bf(float f) {
  unsigned int u = __float_as_uint(f);
  u += 0x7fff + ((u >> 16) & 1);  // round-to-nearest-even
  return (unsigned short)(u >> 16);
}

// ---------------------------------------------------------------------------
// Kernel 0: weight precompute.
// WB  [768][64]  = [Wq;Wk;Wv]^T rows c, cols f   (bf16)
// WoT [256][256] = Wo^T rows co, cols c          (bf16)
// ---------------------------------------------------------------------------
__global__ __launch_bounds__(256) void k_prep(
    const float* __restrict__ Wq, const float* __restrict__ Wk,
    const float* __restrict__ Wv, const float* __restrict__ Wo,
    unsigned short* __restrict__ WB, unsigned short* __restrict__ WoT) {
  int i = blockIdx.x * 256 + threadIdx.x;
  const int total = 768 * 64 + 256 * 256;
  for (; i < total; i += gridDim.x * 256) {
    if (i < 768 * 64) {
      int c = i >> 6, f = i & 63;
      int arr = c >> 8, cc = c & 255;
      const float* W = (arr == 0) ? Wq : (arr == 1) ? Wk : Wv;
      WB[i] = f2bf(W[f * 256 + cc]);
    } else {
      int j = i - 768 * 64;
      int co = j >> 8, c = j & 255;
      WoT[j] = f2bf(Wo[c * 256 + co]);
    }
  }
}

// ---------------------------------------------------------------------------
// Kernel 1: QKV projection. Block = (bn, 128-row t-chunk), 256 thr.
// Q pre-scaled by 0.125*log2(e) (softmax done in exp2 domain downstream).
// Q,K out: [bn][h][t][d] bf16. V out: [bn][h][d][t] via per-wave LDS bounce.
// ---------------------------------------------------------------------------
__global__ __launch_bounds__(256) void k_qkv(
    const float* __restrict__ x, const unsigned short* __restrict__ WB,
    const float* __restrict__ bq, const float* __restrict__ bk,
    const float* __restrict__ bv,
    unsigned short* __restrict__ Qw, unsigned short* __restrict__ Kw,
    unsigned short* __restrict__ Vw, int bn0) {
  // overlay: xT [128][72] u16 (18432 B) , then per-wave V bounce [16][144] u16
  __shared__ __align__(16) unsigned short shm[9216];

  const int tid = threadIdx.x;
  const int lbn = blockIdx.x >> 2;
  const int tch = blockIdx.x & 3;
  const float* xb = x + (size_t)(bn0 + lbn) * kF * kT + tch * 128;

  // stage x^T chunk as bf16 (float4 global loads)
  for (int idx = tid; idx < 2048; idx += 256) {
    int f = idx >> 5, t4 = idx & 31;
    float4 v = *(const float4*)(xb + f * kT + t4 * 4);
    shm[(t4 * 4 + 0) * 72 + f] = f2bf(v.x);
    shm[(t4 * 4 + 1) * 72 + f] = f2bf(v.y);
    shm[(t4 * 4 + 2) * 72 + f] = f2bf(v.z);
    shm[(t4 * 4 + 3) * 72 + f] = f2bf(v.w);
  }
  __syncthreads();

  const int lane = tid & 63, wid = tid >> 6;
  const int lr = lane & 15, lg = lane >> 4;

  // preload all B-frags (xT) for this wave, then free shm for bounce use
  s16x8 bfr[8][2];
#pragma unroll
  for (int tj = 0; tj < 8; ++tj)
#pragma unroll
    for (int kk = 0; kk < 2; ++kk)
      bfr[tj][kk] = *(const s16x8*)&shm[(tj * 16 + lr) * 72 + kk * 32 + lg * 8];
  __syncthreads();

  const float kQscale = 0.180336880111120426f;  // 0.125 * log2(e)

  for (int i = 0; i < 12; ++i) {
    const int ci = wid * 12 + i;
    const int c0 = ci * 16;
    s16x8 af0 = *(const s16x8*)(WB + (size_t)(c0 + lr) * 64 + lg * 8);
    s16x8 af1 = *(const s16x8*)(WB + (size_t)(c0 + lr) * 64 + 32 + lg * 8);

    f32x4 acc[8];
#pragma unroll
    for (int tj = 0; tj < 8; ++tj) {
      f32x4 a = {0.f, 0.f, 0.f, 0.f};
      a = __builtin_amdgcn_mfma_f32_16x16x32_bf16(af0, bfr[tj][0], a, 0, 0, 0);
      a = __builtin_amdgcn_mfma_f32_16x16x32_bf16(af1, bfr[tj][1], a, 0, 0, 0);
      acc[tj] = a;
    }

    const int arr = c0 >> 8;
    const int h = (c0 & 255) >> 6;
    const int dbase0 = (c0 & 63);
    const int dbase = dbase0 + lg * 4;
    const float* bsrc = (arr == 0) ? bq : (arr == 1) ? bk : bv;
    float b0 = bsrc[h * 64 + dbase + 0];
    float b1 = bsrc[h * 64 + dbase + 1];
    float b2 = bsrc[h * 64 + dbase + 2];
    float b3 = bsrc[h * 64 + dbase + 3];

    if (arr < 2) {
      const float scale = (arr == 0) ? kQscale : 1.0f;
      unsigned short* dst = ((arr == 0) ? Qw : Kw) +
                            (size_t)(lbn * kH + h) * kT * kHD;
#pragma unroll
      for (int tj = 0; tj < 8; ++tj) {
        int t = tch * 128 + tj * 16 + lr;
        float v0 = (acc[tj][0] + b0) * scale;
        float v1 = (acc[tj][1] + b1) * scale;
        float v2 = (acc[tj][2] + b2) * scale;
        float v3 = (acc[tj][3] + b3) * scale;
        unsigned long long pk =
            (unsigned long long)f2bf(v0) |
            ((unsigned long long)f2bf(v1) << 16) |
            ((unsigned long long)f2bf(v2) << 32) |
            ((unsigned long long)f2bf(v3) << 48);
        *(unsigned long long*)(dst + (size_t)t * kHD + dbase) = pk;
      }
    } else {
      // V^T tile via per-wave LDS bounce: [16 d][128 t] -> coalesced stores
      unsigned short* buf = shm + wid * (16 * 144);
#pragma unroll
      for (int tj = 0; tj < 8; ++tj) {
        buf[(lg * 4 + 0) * 144 + tj * 16 + lr] = f2bf(acc[tj][0] + b0);
        buf[(lg * 4 + 1) * 144 + tj * 16 + lr] = f2bf(acc[tj][1] + b1);
        buf[(lg * 4 + 2) * 144 + tj * 16 + lr] = f2bf(acc[tj][2] + b2);
        buf[(lg * 4 + 3) * 144 + tj * 16 + lr] = f2bf(acc[tj][3] + b3);
      }
      asm volatile("s_waitcnt lgkmcnt(0)" ::: "memory");
      unsigned short* dst = Vw + (size_t)(lbn * kH + h) * kHD * kT;
      const int row = lane >> 2, cc = lane & 3;
#pragma unroll
      for (int q4 = 0; q4 < 4; ++q4) {
        uint4 vv = *(const uint4*)&buf[row * 144 + (q4 * 4 + cc) * 8];
        *(uint4*)(dst + (size_t)(dbase0 + row) * kT + tch * 128 +
                  (q4 * 4 + cc) * 8) = vv;
      }
    }
  }
}

// ---------------------------------------------------------------------------
// Kernel 2: flash attention per (bn, head). 1024 threads = 16 waves.
// Swapped QK^T -> scores [k][q], k lane-local. Softmax in exp2 domain
// (log2e folded into Q). P stays entirely in registers: the PV k-order is
// permuted (pi-trick) so the cvt_pk words ARE the A-fragment; V^T is read
// as 2x b64 per fragment with matching permuted columns. Defer-rescale
// (THR=8 in log2 domain) skips o-rescale on most iterations.
// ---------------------------------------------------------------------------
__global__ __launch_bounds__(1024, 4) void k_attn(
    const unsigned short* __restrict__ Qw, const unsigned short* __restrict__ Kw,
    const unsigned short* __restrict__ Vw, unsigned short* __restrict__ Aw) {
  __shared__ __align__(16) unsigned char KlB[512 * 128];   // [k][d] swizzled
  __shared__ __align__(16) unsigned char VtB[64 * 1024];   // [d][t] swizzled

  const int tid = threadIdx.x;
  const int lbn = blockIdx.x >> 2;
  const int h = blockIdx.x & 3;
  const size_t hb = (size_t)(lbn * kH + h) * kT * kHD;

  const uint4* Ksrc = (const uint4*)(Kw + hb);
  const uint4* Vsrc = (const uint4*)(Vw + hb);
#pragma unroll
  for (int i = 0; i < 4; ++i) {
    int cidx = tid + i * 1024;
    int t = cidx >> 3, c8 = cidx & 7;
    *(uint4*)(KlB + ((t * 128 + c8 * 16) ^ ((t & 7) << 4))) = Ksrc[cidx];
    int d = cidx >> 6, t8 = cidx & 63;
    *(uint4*)(VtB + ((d * 1024 + t8 * 16) ^ ((d & 7) << 4))) = Vsrc[cidx];
  }
  __syncthreads();

  const int lane = tid & 63, wid = tid >> 6;
  const int lr = lane & 15, lg = lane >> 4;
  const int swz = (lr & 7) << 4;
  const unsigned short* Qb = Qw + hb;
  unsigned short* Ab = Aw + (size_t)lbn * kT * kC + h * kHD;

  union PU { unsigned int w[8]; s16x8 v[2]; };
  union VU { uint2 u[2]; s16x8 v; };

  for (int qt = 0; qt < 2; ++qt) {
    const int qbase = wid * 32 + qt * 16;
    s16x8 qf0 = *(const s16x8*)(Qb + (size_t)(qbase + lr) * kHD + lg * 8);
    s16x8 qf1 = *(const s16x8*)(Qb + (size_t)(qbase + lr) * kHD + 32 + lg * 8);

    f32x4 o[4] = {{0,0,0,0},{0,0,0,0},{0,0,0,0},{0,0,0,0}};
    float m = -3e38f, l = 0.f;

    for (int kc = 0; kc < 8; ++kc) {
      const int kb = kc * 64;

      s16x8 kf[4][2];
#pragma unroll
      for (int s = 0; s < 4; ++s) {
        const unsigned char* rp = KlB + (kb + 16 * s + lr) * 128;
        kf[s][0] = *(const s16x8*)(rp + ((lg * 16) ^ swz));
        kf[s][1] = *(const s16x8*)(rp + ((64 + lg * 16) ^ swz));
      }

      // sa[s][r] = S2[k = kb+16s+4lg+r][q = qbase+lr]  (log2 domain)
      f32x4 sa[4];
#pragma unroll
      for (int s = 0; s < 4; ++s) {
        f32x4 z = {0.f, 0.f, 0.f, 0.f};
        z = __builtin_amdgcn_mfma_f32_16x16x32_bf16(kf[s][0], qf0, z, 0, 0, 0);
        z = __builtin_amdgcn_mfma_f32_16x16x32_bf16(kf[s][1], qf1, z, 0, 0, 0);
        sa[s] = z;
      }

      float tm = sa[0][0];
#pragma unroll
      for (int s = 0; s < 4; ++s)
#pragma unroll
        for (int r = 0; r < 4; ++r) tm = fmaxf(tm, sa[s][r]);
      tm = fmaxf(tm, __shfl_xor(tm, 16));
      tm = fmaxf(tm, __shfl_xor(tm, 32));

      if (!__all(tm <= m + 8.0f)) {       // defer-rescale, THR=8 (=2^8 bound)
        float mn = fmaxf(m, tm);
        float al = exp2f(m - mn);
        m = mn;
        float alq[4];
#pragma unroll
        for (int r = 0; r < 4; ++r)
          alq[r] = __shfl(al, (lane & 48) | (lg * 4 + r));
#pragma unroll
        for (int dt = 0; dt < 4; ++dt)
#pragma unroll
          for (int r = 0; r < 4; ++r) o[dt][r] *= alq[r];
        l *= al;
      }

      float p[4][4];
      float rs = 0.f;
#pragma unroll
      for (int s = 0; s < 4; ++s)
#pragma unroll
        for (int r = 0; r < 4; ++r) {
          p[s][r] = exp2f(sa[s][r] - m);
          rs += p[s][r];
        }
      rs += __shfl_xor(rs, 16);
      rs += __shfl_xor(rs, 32);
      l += rs;

      // pack P: W[s][i] = pk(p[s][2i], p[s][2i+1]); A-frag = own words
      PU P8;
#pragma unroll
      for (int s = 0; s < 4; ++s)
#pragma unroll
        for (int i2 = 0; i2 < 2; ++i2)
          asm("v_cvt_pk_bf16_f32 %0, %1, %2"
              : "=v"(P8.w[s * 2 + i2])
              : "v"(p[s][2 * i2]), "v"(p[s][2 * i2 + 1]));

#pragma unroll
      for (int t2 = 0; t2 < 2; ++t2) {
        const int cb = (kb + 32 * t2) * 2 + 8 * lg;
#pragma unroll
        for (int dt = 0; dt < 4; ++dt) {
          const unsigned char* vp = VtB + (dt * 16 + lr) * 1024;
          VU vu;
          vu.u[0] = *(const uint2*)(vp + (cb ^ swz));
          vu.u[1] = *(const uint2*)(vp + ((cb + 32) ^ swz));
          o[dt] = __builtin_amdgcn_mfma_f32_16x16x32_bf16(P8.v[t2], vu.v,
                                                          o[dt], 0, 0, 0);
        }
      }
    }

    float linv[4];
#pragma unroll
    for (int r = 0; r < 4; ++r)
      linv[r] = 1.0f / __shfl(l, (lane & 48) | (lg * 4 + r));
#pragma unroll
    for (int r = 0; r < 4; ++r) {
      int q = qbase + lg * 4 + r;
      unsigned short* orow = Ab + (size_t)q * kC;
#pragma unroll
      for (int dt = 0; dt < 4; ++dt)
        orow[dt * 16 + lr] = f2bf(o[dt][r] * linv[r]);
    }
  }
}

// ---------------------------------------------------------------------------
// Kernel 3: output projection + bias + transpose. Block = (bn, 128-t chunk),
// 512 thr = 8 waves (2 t-halves x 4 co-quads). A staged ONCE in swizzled LDS.
// out[bn][co][t] fp32.
// ---------------------------------------------------------------------------
__global__ __launch_bounds__(512) void k_proj(
    const unsigned short* __restrict__ Aw, const unsigned short* __restrict__ WoT,
    const float* __restrict__ bo, float* __restrict__ out, int bn0) {
  __shared__ __align__(16) unsigned char Al[128 * 512];  // [t][c] swizzled, 64KB

  const int tid = threadIdx.x;
  const int lbn = blockIdx.x >> 2;
  const int tch = blockIdx.x & 3;
  const int t0 = tch * 128;

  const uint4* Asrc = (const uint4*)(Aw + ((size_t)lbn * kT + t0) * kC);
#pragma unroll
  for (int i = 0; i < 8; ++i) {
    int idx = tid + i * 512;
    int trow = idx >> 5, cc = idx & 31;
    *(uint4*)(Al + ((trow * 512 + cc * 16) ^ ((trow & 7) << 4))) = Asrc[idx];
  }
  __syncthreads();

  const int lane = tid & 63, wid = tid >> 6;
  const int lr = lane & 15, lg = lane >> 4;
  const int swz = (lr & 7) << 4;
  const int tb = (wid >> 2) * 64;
  const int cob = (wid & 3) * 64;

  float* ob = out + (size_t)(bn0 + lbn) * kC * kT;

  for (int ci = 0; ci < 4; ++ci) {
    const int co0 = cob + ci * 16;
    s16x8 af[8];
#pragma unroll
    for (int kc = 0; kc < 8; ++kc)
      af[kc] = *(const s16x8*)(WoT + (size_t)(co0 + lr) * 256 + kc * 32 + lg * 8);
    float b4[4];
#pragma unroll
    for (int r = 0; r < 4; ++r) b4[r] = bo[co0 + lg * 4 + r];

#pragma unroll
    for (int tj = 0; tj < 4; ++tj) {
      const unsigned char* ap = Al + (tb + tj * 16 + lr) * 512;
      f32x4 acc = {0.f, 0.f, 0.f, 0.f};
#pragma unroll
      for (int kc = 0; kc < 8; ++kc) {
        s16x8 bfr = *(const s16x8*)(ap + ((kc * 64 + lg * 16) ^ swz));
        acc = __builtin_amdgcn_mfma_f32_16x16x32_bf16(af[kc], bfr, acc, 0, 0, 0);
      }
      int t = t0 + tb + tj * 16 + lr;
#pragma unroll
      for (int r = 0; r < 4; ++r)
        ob[(size_t)(co0 + lg * 4 + r) * kT + t] = acc[r] + b4[r];
    }
  }
}

// ---------------------------------------------------------------------------
extern "C" void kernel_launch(void* const* d_in, const int* in_sizes, int n_in,
                              void* d_out, int out_size, void* d_ws, size_t ws_size,
                              hipStream_t stream) {
  const float* x  = (const float*)d_in[0];
  const float* Wq = (const float*)d_in[1];
  const float* bq = (const float*)d_in[2];
  const float* Wk = (const float*)d_in[3];
  const float* bk = (const float*)d_in[4];
  const float* Wv = (const float*)d_in[5];
  const float* bv = (const float*)d_in[6];
  const float* Wo = (const float*)d_in[7];
  const float* bo = (const float*)d_in[8];
  float* out = (float*)d_out;

  const size_t wElems = 768 * 64 + 256 * 256;
  const size_t perbn = (size_t)4 * kT * kC * 2;    // 1 MB
  if (ws_size < wElems * 2 + perbn) return;
  int cap = (int)((ws_size - wElems * 2) / perbn);
  if (cap > kBN) cap = kBN;

  unsigned short* WB  = (unsigned short*)d_ws;
  unsigned short* WoT = WB + 768 * 64;
  unsigned short* Q = WB + wElems;
  unsigned short* K = Q + (size_t)cap * kT * kC;
  unsigned short* V = K + (size_t)cap * kT * kC;
  unsigned short* A = V + (size_t)cap * kT * kC;

  k_prep<<<dim3(448), dim3(256), 0, stream>>>(Wq, Wk, Wv, Wo, WB, WoT);

  for (int s = 0; s < kBN; s += cap) {
    int nb = (kBN - s < cap) ? (kBN - s) : cap;
    k_qkv<<<dim3(nb * 4), dim3(256), 0, stream>>>(x, WB, bq, bk, bv,
                                                  Q, K, V, s);
    k_attn<<<dim3(nb * 4), dim3(1024), 0, stream>>>(Q, K, V, A);
    k_proj<<<dim3(nb * 4), dim3(512), 0, stream>>>(A, WoT, bo, out, s);
  }
}

// Round 5
// 134.014 us; speedup vs baseline: 2.1831x; 1.1421x over previous
//
#include <hip/hip_runtime.h>

// Problem constants
constexpr int kT = 512;     // sequence length
constexpr int kF = 64;      // input features
constexpr int kC = 256;     // f_out
constexpr int kH = 4;       // heads
constexpr int kHD = 64;     // head dim
constexpr int kBN = 128;    // B*N independent problems

typedef __attribute__((ext_vector_type(4))) float f32x4;
typedef __attribute__((ext_vector_type(8))) short s16x8;
typedef __attribute__((ext_vector_type(4))) unsigned int u32x4;

__device__ inline unsigned short f2bf(float f) {
  unsigned int u = __float_as_uint(f);
  u += 0x7fff + ((u >> 16) & 1);  // round-to-nearest-even
  return (unsigned short)(u >> 16);
}

__device__ inline float max3f(float a, float b, float c) {
  return fmaxf(fmaxf(a, b), c);   // fuses to v_max3_f32
}

__device__ inline float exp2_hw(float x) {
  float r;
  asm("v_exp_f32 %0, %1" : "=v"(r) : "v"(x));
  return r;
}

// ---------------------------------------------------------------------------
// Kernel 0: weight precompute.
// WB  [768][64]  = [Wq;Wk;Wv]^T rows c, cols f   (bf16)
// WoT [256][256] = Wo^T rows co, cols c          (bf16)
// ---------------------------------------------------------------------------
__global__ __launch_bounds__(256) void k_prep(
    const float* __restrict__ Wq, const float* __restrict__ Wk,
    const float* __restrict__ Wv, const float* __restrict__ Wo,
    unsigned short* __restrict__ WB, unsigned short* __restrict__ WoT) {
  int i = blockIdx.x * 256 + threadIdx.x;
  const int total = 768 * 64 + 256 * 256;
  for (; i < total; i += gridDim.x * 256) {
    if (i < 768 * 64) {
      int c = i >> 6, f = i & 63;
      int arr = c >> 8, cc = c & 255;
      const float* W = (arr == 0) ? Wq : (arr == 1) ? Wk : Wv;
      WB[i] = f2bf(W[f * 256 + cc]);
    } else {
      int j = i - 768 * 64;
      int co = j >> 8, c = j & 255;
      WoT[j] = f2bf(Wo[c * 256 + co]);
    }
  }
}

// ---------------------------------------------------------------------------
// Kernel 1: QKV projection. Block = (bn, 128-row t-chunk), 256 thr.
// Q pre-scaled by 0.125*log2(e) (softmax done in exp2 domain downstream).
// Q,K out: [bn][h][t][d] bf16. V out: [bn][h][d][t] via per-wave LDS bounce.
// ---------------------------------------------------------------------------
__global__ __launch_bounds__(256) void k_qkv(
    const float* __restrict__ x, const unsigned short* __restrict__ WB,
    const float* __restrict__ bq, const float* __restrict__ bk,
    const float* __restrict__ bv,
    unsigned short* __restrict__ Qw, unsigned short* __restrict__ Kw,
    unsigned short* __restrict__ Vw, int bn0) {
  // overlay: xT [128][72] u16 (18432 B) , then per-wave V bounce [16][144] u16
  __shared__ __align__(16) unsigned short shm[9216];

  const int tid = threadIdx.x;
  const int lbn = blockIdx.x >> 2;
  const int tch = blockIdx.x & 3;
  const float* xb = x + (size_t)(bn0 + lbn) * kF * kT + tch * 128;

  // stage x^T chunk as bf16 (float4 global loads)
  for (int idx = tid; idx < 2048; idx += 256) {
    int f = idx >> 5, t4 = idx & 31;
    float4 v = *(const float4*)(xb + f * kT + t4 * 4);
    shm[(t4 * 4 + 0) * 72 + f] = f2bf(v.x);
    shm[(t4 * 4 + 1) * 72 + f] = f2bf(v.y);
    shm[(t4 * 4 + 2) * 72 + f] = f2bf(v.z);
    shm[(t4 * 4 + 3) * 72 + f] = f2bf(v.w);
  }
  __syncthreads();

  const int lane = tid & 63, wid = tid >> 6;
  const int lr = lane & 15, lg = lane >> 4;

  // preload all B-frags (xT) for this wave, then free shm for bounce use
  s16x8 bfr[8][2];
#pragma unroll
  for (int tj = 0; tj < 8; ++tj)
#pragma unroll
    for (int kk = 0; kk < 2; ++kk)
      bfr[tj][kk] = *(const s16x8*)&shm[(tj * 16 + lr) * 72 + kk * 32 + lg * 8];
  __syncthreads();

  const float kQscale = 0.180336880111120426f;  // 0.125 * log2(e)

  for (int i = 0; i < 12; ++i) {
    const int ci = wid * 12 + i;
    const int c0 = ci * 16;
    s16x8 af0 = *(const s16x8*)(WB + (size_t)(c0 + lr) * 64 + lg * 8);
    s16x8 af1 = *(const s16x8*)(WB + (size_t)(c0 + lr) * 64 + 32 + lg * 8);

    f32x4 acc[8];
#pragma unroll
    for (int tj = 0; tj < 8; ++tj) {
      f32x4 a = {0.f, 0.f, 0.f, 0.f};
      a = __builtin_amdgcn_mfma_f32_16x16x32_bf16(af0, bfr[tj][0], a, 0, 0, 0);
      a = __builtin_amdgcn_mfma_f32_16x16x32_bf16(af1, bfr[tj][1], a, 0, 0, 0);
      acc[tj] = a;
    }

    const int arr = c0 >> 8;
    const int h = (c0 & 255) >> 6;
    const int dbase0 = (c0 & 63);
    const int dbase = dbase0 + lg * 4;
    const float* bsrc = (arr == 0) ? bq : (arr == 1) ? bk : bv;
    float b0 = bsrc[h * 64 + dbase + 0];
    float b1 = bsrc[h * 64 + dbase + 1];
    float b2 = bsrc[h * 64 + dbase + 2];
    float b3 = bsrc[h * 64 + dbase + 3];

    if (arr < 2) {
      const float scale = (arr == 0) ? kQscale : 1.0f;
      unsigned short* dst = ((arr == 0) ? Qw : Kw) +
                            (size_t)(lbn * kH + h) * kT * kHD;
#pragma unroll
      for (int tj = 0; tj < 8; ++tj) {
        int t = tch * 128 + tj * 16 + lr;
        float v0 = (acc[tj][0] + b0) * scale;
        float v1 = (acc[tj][1] + b1) * scale;
        float v2 = (acc[tj][2] + b2) * scale;
        float v3 = (acc[tj][3] + b3) * scale;
        unsigned long long pk =
            (unsigned long long)f2bf(v0) |
            ((unsigned long long)f2bf(v1) << 16) |
            ((unsigned long long)f2bf(v2) << 32) |
            ((unsigned long long)f2bf(v3) << 48);
        *(unsigned long long*)(dst + (size_t)t * kHD + dbase) = pk;
      }
    } else {
      // V^T tile via per-wave LDS bounce: [16 d][128 t] -> coalesced stores
      unsigned short* buf = shm + wid * (16 * 144);
#pragma unroll
      for (int tj = 0; tj < 8; ++tj) {
        buf[(lg * 4 + 0) * 144 + tj * 16 + lr] = f2bf(acc[tj][0] + b0);
        buf[(lg * 4 + 1) * 144 + tj * 16 + lr] = f2bf(acc[tj][1] + b1);
        buf[(lg * 4 + 2) * 144 + tj * 16 + lr] = f2bf(acc[tj][2] + b2);
        buf[(lg * 4 + 3) * 144 + tj * 16 + lr] = f2bf(acc[tj][3] + b3);
      }
      asm volatile("s_waitcnt lgkmcnt(0)" ::: "memory");
      unsigned short* dst = Vw + (size_t)(lbn * kH + h) * kHD * kT;
      const int row = lane >> 2, cc = lane & 3;
#pragma unroll
      for (int q4 = 0; q4 < 4; ++q4) {
        uint4 vv = *(const uint4*)&buf[row * 144 + (q4 * 4 + cc) * 8];
        *(uint4*)(dst + (size_t)(dbase0 + row) * kT + tch * 128 +
                  (q4 * 4 + cc) * 8) = vv;
      }
    }
  }
}

// ---------------------------------------------------------------------------
// Kernel 2: flash attention per (bn, head). 1024 threads = 16 waves.
// Swapped QK^T -> scores [k][q], k lane-local; softmax exp2-domain, fully
// in-register. Per wave: 32 q rows, both 16-row q-tiles share each kc's
// K-frags and V-frags (one LDS read feeds 4 MFMAs). V is stored to LDS
// pre-permuted (kappa) so PV B-frags are single b128 reads. All LDS
// addressing hoisted to 6 base pointers + immediate offsets. Per-lane
// partial l (cross-lane sum at epilogue only); __any defer-max: common
// path has ZERO cross-lane ops.
// ---------------------------------------------------------------------------
__global__ __launch_bounds__(1024, 4) void k_attn(
    const unsigned short* __restrict__ Qw, const unsigned short* __restrict__ Kw,
    const unsigned short* __restrict__ Vw, unsigned short* __restrict__ Aw) {
  __shared__ __align__(16) unsigned char KlB[512 * 128];   // [k][d] swizzled
  __shared__ __align__(16) unsigned char VtB[64 * 1024];   // [d][pos] swizzled

  const int tid = threadIdx.x;
  const int lbn = blockIdx.x >> 2;
  const int h = blockIdx.x & 3;
  const size_t hb = (size_t)(lbn * kH + h) * kT * kHD;

  // --- stage K (swizzled rows) ---
  const uint4* Ksrc = (const uint4*)(Kw + hb);
#pragma unroll
  for (int i = 0; i < 4; ++i) {
    int cidx = tid + i * 1024;
    int t = cidx >> 3, c8 = cidx & 7;
    *(uint4*)(KlB + ((t * 128 + c8 * 16) ^ ((t & 7) << 4))) = Ksrc[cidx];
  }
  // --- stage V^T with kappa pre-permutation (8-byte granularity) ---
  // position p = 8h+u (within 32-block) holds key 16*(u>>2) + 4*h + (u&3)
  const unsigned short* Vs = Vw + hb;
#pragma unroll
  for (int i = 0; i < 8; ++i) {
    int gi = tid + i * 1024;            // 8-byte group index, [0, 8192)
    int d = gi >> 7, gr = gi & 127;
    int b32 = gr >> 3, g2 = gr & 7;
    int hh = g2 >> 1, e = g2 & 1;
    uint2 v = *(const uint2*)(Vs + d * 512 + b32 * 32 + e * 16 + hh * 4);
    *(uint2*)(VtB + ((d * 1024 + gr * 8) ^ ((d & 7) << 4))) = v;
  }
  __syncthreads();

  const int lane = tid & 63, wid = tid >> 6;
  const int lr = lane & 15, lg = lane >> 4;
  const int swz = (lr & 7) << 4;
  const unsigned short* Qb = Qw + hb;
  unsigned short* Ab = Aw + (size_t)lbn * kT * kC + h * kHD;

  const int qbase = wid * 32;
  s16x8 qf[2][2];
#pragma unroll
  for (int qt = 0; qt < 2; ++qt) {
    qf[qt][0] = *(const s16x8*)(Qb + (size_t)(qbase + qt * 16 + lr) * kHD + lg * 8);
    qf[qt][1] = *(const s16x8*)(Qb + (size_t)(qbase + qt * 16 + lr) * kHD + 32 + lg * 8);
  }

  f32x4 o0[4] = {{0,0,0,0},{0,0,0,0},{0,0,0,0},{0,0,0,0}};
  f32x4 o1[4] = {{0,0,0,0},{0,0,0,0},{0,0,0,0},{0,0,0,0}};
  float m0 = -3e38f, m1 = -3e38f, l0 = 0.f, l1 = 0.f;

  // hoisted LDS base pointers (advanced by constants per kc)
  const int koff = (lg * 16) ^ swz;
  const unsigned char* kp0 = KlB + lr * 128 + koff;
  const unsigned char* kp1 = KlB + lr * 128 + (koff ^ 64);
  const int voff = (lg * 16) ^ swz;
  const unsigned char* vp0 = VtB + lr * 1024 + voff;          // t2 = 0
  const unsigned char* vp1 = VtB + lr * 1024 + (voff ^ 64);   // t2 = 1

  unsigned int w0[8], w1[8];

#define SOFTMAX_QT(sa, m, l, o, w)                                            \
  {                                                                           \
    float g0 = max3f(sa[0][0], sa[0][1], sa[0][2]);                           \
    float g1 = max3f(sa[0][3], sa[1][0], sa[1][1]);                           \
    float g2 = max3f(sa[1][2], sa[1][3], sa[2][0]);                           \
    float g3 = max3f(sa[2][1], sa[2][2], sa[2][3]);                           \
    float g4 = max3f(sa[3][0], sa[3][1], sa[3][2]);                           \
    float tm = fmaxf(max3f(g0, g1, g2), max3f(g3, g4, sa[3][3]));             \
    if (__any(tm > m + 8.0f)) {                                               \
      tm = fmaxf(tm, __shfl_xor(tm, 16));                                     \
      tm = fmaxf(tm, __shfl_xor(tm, 32));                                     \
      float mn = fmaxf(m, tm);                                                \
      float al = exp2_hw(m - mn);                                             \
      m = mn;                                                                 \
      l *= al;                                                                \
      float aq0 = __shfl(al, (lane & 48) | (lg * 4 + 0));                     \
      float aq1 = __shfl(al, (lane & 48) | (lg * 4 + 1));                     \
      float aq2 = __shfl(al, (lane & 48) | (lg * 4 + 2));                     \
      float aq3 = __shfl(al, (lane & 48) | (lg * 4 + 3));                     \
      _Pragma("unroll")                                                       \
      for (int dt = 0; dt < 4; ++dt) {                                        \
        o[dt][0] *= aq0; o[dt][1] *= aq1;                                     \
        o[dt][2] *= aq2; o[dt][3] *= aq3;                                     \
      }                                                                       \
    }                                                                         \
    _Pragma("unroll")                                                         \
    for (int s = 0; s < 4; ++s) {                                             \
      float e0 = exp2_hw(sa[s][0] - m);                                       \
      float e1 = exp2_hw(sa[s][1] - m);                                       \
      float e2 = exp2_hw(sa[s][2] - m);                                       \
      float e3 = exp2_hw(sa[s][3] - m);                                       \
      l += (e0 + e1) + (e2 + e3);                                             \
      asm("v_cvt_pk_bf16_f32 %0, %1, %2" : "=v"(w[2*s]) : "v"(e0), "v"(e1));  \
      asm("v_cvt_pk_bf16_f32 %0, %1, %2" : "=v"(w[2*s+1]) : "v"(e2), "v"(e3));\
    }                                                                         \
  }

  for (int kc = 0; kc < 8; ++kc) {
    f32x4 sa0[4], sa1[4];
#pragma unroll
    for (int s = 0; s < 4; ++s) {
      s16x8 kf0 = *(const s16x8*)(kp0 + s * 2048);
      s16x8 kf1 = *(const s16x8*)(kp1 + s * 2048);
      f32x4 z0 = {0.f, 0.f, 0.f, 0.f};
      z0 = __builtin_amdgcn_mfma_f32_16x16x32_bf16(kf0, qf[0][0], z0, 0, 0, 0);
      z0 = __builtin_amdgcn_mfma_f32_16x16x32_bf16(kf1, qf[0][1], z0, 0, 0, 0);
      sa0[s] = z0;
      f32x4 z1 = {0.f, 0.f, 0.f, 0.f};
      z1 = __builtin_amdgcn_mfma_f32_16x16x32_bf16(kf0, qf[1][0], z1, 0, 0, 0);
      z1 = __builtin_amdgcn_mfma_f32_16x16x32_bf16(kf1, qf[1][1], z1, 0, 0, 0);
      sa1[s] = z1;
    }
    kp0 += 8192;
    kp1 += 8192;

    SOFTMAX_QT(sa0, m0, l0, o0, w0)
    SOFTMAX_QT(sa1, m1, l1, o1, w1)

    s16x8 pa00 = __builtin_bit_cast(s16x8, (u32x4){w0[0], w0[1], w0[2], w0[3]});
    s16x8 pa01 = __builtin_bit_cast(s16x8, (u32x4){w0[4], w0[5], w0[6], w0[7]});
    s16x8 pa10 = __builtin_bit_cast(s16x8, (u32x4){w1[0], w1[1], w1[2], w1[3]});
    s16x8 pa11 = __builtin_bit_cast(s16x8, (u32x4){w1[4], w1[5], w1[6], w1[7]});

#pragma unroll
    for (int dt = 0; dt < 4; ++dt) {
      s16x8 vb = *(const s16x8*)(vp0 + dt * 16384);
      o0[dt] = __builtin_amdgcn_mfma_f32_16x16x32_bf16(pa00, vb, o0[dt], 0, 0, 0);
      o1[dt] = __builtin_amdgcn_mfma_f32_16x16x32_bf16(pa10, vb, o1[dt], 0, 0, 0);
    }
#pragma unroll
    for (int dt = 0; dt < 4; ++dt) {
      s16x8 vb = *(const s16x8*)(vp1 + dt * 16384);
      o0[dt] = __builtin_amdgcn_mfma_f32_16x16x32_bf16(pa01, vb, o0[dt], 0, 0, 0);
      o1[dt] = __builtin_amdgcn_mfma_f32_16x16x32_bf16(pa11, vb, o1[dt], 0, 0, 0);
    }
    vp0 += 128;
    vp1 += 128;
  }
#undef SOFTMAX_QT

  // epilogue: cross-lane l sum, then normalize + write
#pragma unroll
  for (int qt = 0; qt < 2; ++qt) {
    float l = (qt == 0) ? l0 : l1;
    f32x4* o = (qt == 0) ? o0 : o1;
    float l2 = l + __shfl_xor(l, 16);
    float lr4 = l2 + __shfl_xor(l2, 32);
    float li0 = 1.0f / __shfl(lr4, (lane & 48) | (lg * 4 + 0));
    float li1 = 1.0f / __shfl(lr4, (lane & 48) | (lg * 4 + 1));
    float li2 = 1.0f / __shfl(lr4, (lane & 48) | (lg * 4 + 2));
    float li3 = 1.0f / __shfl(lr4, (lane & 48) | (lg * 4 + 3));
    const int qb = qbase + qt * 16;
#pragma unroll
    for (int r = 0; r < 4; ++r) {
      float li = (r == 0) ? li0 : (r == 1) ? li1 : (r == 2) ? li2 : li3;
      unsigned short* orow = Ab + (size_t)(qb + lg * 4 + r) * kC;
#pragma unroll
      for (int dt = 0; dt < 4; ++dt)
        orow[dt * 16 + lr] = f2bf(o[dt][r] * li);
    }
  }
}

// ---------------------------------------------------------------------------
// Kernel 3: output projection + bias + transpose. Block = (bn, 128-t chunk),
// 512 thr = 8 waves (2 t-halves x 4 co-quads). A staged ONCE in swizzled LDS.
// out[bn][co][t] fp32.
// ---------------------------------------------------------------------------
__global__ __launch_bounds__(512) void k_proj(
    const unsigned short* __restrict__ Aw, const unsigned short* __restrict__ WoT,
    const float* __restrict__ bo, float* __restrict__ out, int bn0) {
  __shared__ __align__(16) unsigned char Al[128 * 512];  // [t][c] swizzled, 64KB

  const int tid = threadIdx.x;
  const int lbn = blockIdx.x >> 2;
  const int tch = blockIdx.x & 3;
  const int t0 = tch * 128;

  const uint4* Asrc = (const uint4*)(Aw + ((size_t)lbn * kT + t0) * kC);
#pragma unroll
  for (int i = 0; i < 8; ++i) {
    int idx = tid + i * 512;
    int trow = idx >> 5, cc = idx & 31;
    *(uint4*)(Al + ((trow * 512 + cc * 16) ^ ((trow & 7) << 4))) = Asrc[idx];
  }
  __syncthreads();

  const int lane = tid & 63, wid = tid >> 6;
  const int lr = lane & 15, lg = lane >> 4;
  const int swz = (lr & 7) << 4;
  const int tb = (wid >> 2) * 64;
  const int cob = (wid & 3) * 64;

  float* ob = out + (size_t)(bn0 + lbn) * kC * kT;

  for (int ci = 0; ci < 4; ++ci) {
    const int co0 = cob + ci * 16;
    s16x8 af[8];
#pragma unroll
    for (int kc = 0; kc < 8; ++kc)
      af[kc] = *(const s16x8*)(WoT + (size_t)(co0 + lr) * 256 + kc * 32 + lg * 8);
    float b4[4];
#pragma unroll
    for (int r = 0; r < 4; ++r) b4[r] = bo[co0 + lg * 4 + r];

#pragma unroll
    for (int tj = 0; tj < 4; ++tj) {
      const unsigned char* ap = Al + (tb + tj * 16 + lr) * 512;
      f32x4 acc = {0.f, 0.f, 0.f, 0.f};
#pragma unroll
      for (int kc = 0; kc < 8; ++kc) {
        s16x8 bfr = *(const s16x8*)(ap + ((kc * 64 + lg * 16) ^ swz));
        acc = __builtin_amdgcn_mfma_f32_16x16x32_bf16(af[kc], bfr, acc, 0, 0, 0);
      }
      int t = t0 + tb + tj * 16 + lr;
#pragma unroll
      for (int r = 0; r < 4; ++r)
        ob[(size_t)(co0 + lg * 4 + r) * kT + t] = acc[r] + b4[r];
    }
  }
}

// ---------------------------------------------------------------------------
extern "C" void kernel_launch(void* const* d_in, const int* in_sizes, int n_in,
                              void* d_out, int out_size, void* d_ws, size_t ws_size,
                              hipStream_t stream) {
  const float* x  = (const float*)d_in[0];
  const float* Wq = (const float*)d_in[1];
  const float* bq = (const float*)d_in[2];
  const float* Wk = (const float*)d_in[3];
  const float* bk = (const float*)d_in[4];
  const float* Wv = (const float*)d_in[5];
  const float* bv = (const float*)d_in[6];
  const float* Wo = (const float*)d_in[7];
  const float* bo = (const float*)d_in[8];
  float* out = (float*)d_out;

  const size_t wElems = 768 * 64 + 256 * 256;
  const size_t perbn = (size_t)4 * kT * kC * 2;    // 1 MB
  if (ws_size < wElems * 2 + perbn) return;
  int cap = (int)((ws_size - wElems * 2) / perbn);
  if (cap > kBN) cap = kBN;

  unsigned short* WB  = (unsigned short*)d_ws;
  unsigned short* WoT = WB + 768 * 64;
  unsigned short* Q = WB + wElems;
  unsigned short* K = Q + (size_t)cap * kT * kC;
  unsigned short* V = K + (size_t)cap * kT * kC;
  unsigned short* A = V + (size_t)cap * kT * kC;

  k_prep<<<dim3(448), dim3(256), 0, stream>>>(Wq, Wk, Wv, Wo, WB, WoT);

  for (int s = 0; s < kBN; s += cap) {
    int nb = (kBN - s < cap) ? (kBN - s) : cap;
    k_qkv<<<dim3(nb * 4), dim3(256), 0, stream>>>(x, WB, bq, bk, bv,
                                                  Q, K, V, s);
    k_attn<<<dim3(nb * 4), dim3(1024), 0, stream>>>(Q, K, V, A);
    k_proj<<<dim3(nb * 4), dim3(512), 0, stream>>>(A, WoT, bo, out, s);
  }
}